// Round 3
// baseline (1985.633 us; speedup 1.0000x reference)
//
#include <hip/hip_runtime.h>
#include <math.h>

#define B_ROWS 16384
#define H_DIM 7168
#define N_EXP 256
#define KT 32
#define MT 64
#define ET 128

using v4d = __attribute__((ext_vector_type(4))) double;

// Router GEMM, f64 accumulation, with a runtime-probed fast path.
//
// Tile 64 rows x 128 experts, KT=32, 256 threads (4 waves). Shared f32 LDS
// staging; two logical layouts selected at runtime by MFMA layout probes:
//   MFMA path: Ast[m][kk'] stride 36, Wst[e][kk'] stride 36, where
//              kk' = 8*(k%4) + k/4  (lane-group kg reads kk' in [8kg,8kg+8))
//   VALU path: Af[k][m] stride 68,  Wf[k][e] stride 132 (f32 port of the
//              proven baseline; per-(row,expert) k-sequential f64 fma chain
//              is bit-identical to the previously passing kernel)
// Probes run 3 calibration MFMAs through the same read path with integer
// patterns; exact f64 equality required. Any mismatch -> VALU path.
__global__ __launch_bounds__(256, 2)
void router_gemm(const float* __restrict__ hs, const float* __restrict__ w,
                 float* __restrict__ scores) {
    __shared__ float AfU[2304];   // max(32*68, 64*36)
    __shared__ float WfU[4608];   // max(32*132, 128*36)
    __shared__ int okSh;

    const int t = threadIdx.x;
    const int lane = t & 63;
    const int wv = t >> 6;        // wave 0..3
    const int fm = lane & 15;     // mfma: fragment index within 16
    const int kg = lane >> 4;     // mfma: k-group 0..3
    const int tx = t & 15;        // valu: expert group
    const int ty = t >> 4;        // valu: row group
    const int row8 = t >> 3;      // staging: 0..31
    const int kq8 = t & 7;        // staging: k-quarter 0..7

    const int mBase = blockIdx.x * MT;
    const int eBase = blockIdx.y * ET;
    const float* hsp = hs + (size_t)mBase * H_DIM;
    const float* wp  = w  + (size_t)eBase * H_DIM;

    // ---------- layout probes ----------
    bool ok = true;
#pragma unroll 1
    for (int p = 0; p < 3; ++p) {
        for (int i = t; i < 64 * 36; i += 256) {
            int m = i / 36, kk = i % 36;
            int k = (kk & 7) * 4 + (kk >> 3);  // inverse of kk' perm (kk>=32 unused)
            AfU[i] = (p == 0) ? (float)(4 * m + k + 1)
                   : (p == 2) ? (float)(k + 1) : 1.0f;
        }
        for (int i = t; i < 128 * 36; i += 256) {
            int e = i / 36, kk = i % 36;
            int k = (kk & 7) * 4 + (kk >> 3);
            WfU[i] = (p == 1) ? (float)(4 * e + k + 1)
                   : (p == 2) ? (float)(k + 1) : 1.0f;
        }
        __syncthreads();
        double a = (double)AfU[fm * 36 + 8 * kg];
        double b = (double)WfU[fm * 36 + 8 * kg];
        v4d z = {0.0, 0.0, 0.0, 0.0};
        v4d pr = __builtin_amdgcn_mfma_f64_16x16x4f64(a, b, z, 0, 0, 0);
#pragma unroll
        for (int r = 0; r < 4; ++r) {
            double ev = (p == 0) ? (double)(16 * (4 * kg + r) + 10)
                      : (p == 1) ? (double)(16 * fm + 10) : 30.0;
            ok = ok && (pr[r] == ev);
        }
        __syncthreads();
    }
    if (t == 0) okSh = 1;
    __syncthreads();
    if (!ok) okSh = 0;   // benign same-value race
    __syncthreads();
    const bool useMfma = (okSh != 0);

    // ---------- accumulators (unioned: only one path live) ----------
    union AccU { double v[4][8]; v4d m[4][2]; } acc;
#pragma unroll
    for (int r = 0; r < 4; ++r)
#pragma unroll
        for (int c = 0; c < 8; ++c) acc.v[r][c] = 0.0;

    // ---------- global prefetch of chunk 0 ----------
    // float4 f = i*1024 + 4t: A row i*32+row8, W expert i*32+row8, k 4*kq8..+3
    float haf[2][4], waf[4][4];
#pragma unroll
    for (int i = 0; i < 2; ++i)
        *(float4*)&haf[i][0] = *(const float4*)(hsp + (size_t)(i * 32 + row8) * H_DIM + 4 * kq8);
#pragma unroll
    for (int i = 0; i < 4; ++i)
        *(float4*)&waf[i][0] = *(const float4*)(wp + (size_t)(i * 32 + row8) * H_DIM + 4 * kq8);

    const int NCHUNK = H_DIM / KT;  // 224
    for (int ch = 0; ch < NCHUNK; ++ch) {
        // registers -> LDS (layout per path)
        if (useMfma) {
#pragma unroll
            for (int i = 0; i < 2; ++i)
#pragma unroll
                for (int j = 0; j < 4; ++j)
                    AfU[(i * 32 + row8) * 36 + 8 * j + kq8] = haf[i][j];
#pragma unroll
            for (int i = 0; i < 4; ++i)
#pragma unroll
                for (int j = 0; j < 4; ++j)
                    WfU[(i * 32 + row8) * 36 + 8 * j + kq8] = waf[i][j];
        } else {
#pragma unroll
            for (int i = 0; i < 2; ++i)
#pragma unroll
                for (int j = 0; j < 4; ++j)
                    AfU[(4 * kq8 + j) * 68 + i * 32 + row8] = haf[i][j];
#pragma unroll
            for (int i = 0; i < 4; ++i)
#pragma unroll
                for (int j = 0; j < 4; ++j)
                    WfU[(4 * kq8 + j) * 132 + i * 32 + row8] = waf[i][j];
        }
        __syncthreads();
        // prefetch next chunk (overlaps compute)
        if (ch + 1 < NCHUNK) {
            const float* hp2 = hsp + (size_t)(ch + 1) * KT;
            const float* wp2 = wp  + (size_t)(ch + 1) * KT;
#pragma unroll
            for (int i = 0; i < 2; ++i)
                *(float4*)&haf[i][0] = *(const float4*)(hp2 + (size_t)(i * 32 + row8) * H_DIM + 4 * kq8);
#pragma unroll
            for (int i = 0; i < 4; ++i)
                *(float4*)&waf[i][0] = *(const float4*)(wp2 + (size_t)(i * 32 + row8) * H_DIM + 4 * kq8);
        }
        if (useMfma) {
            // load fragments once per chunk: a[rs][q], b[cs][q] (f32)
            float afr[4][8], bfr[2][8];
#pragma unroll
            for (int rs = 0; rs < 4; ++rs) {
                const int base = (rs * 16 + fm) * 36 + 8 * kg;
                *(float4*)&afr[rs][0] = *(float4*)&AfU[base];
                *(float4*)&afr[rs][4] = *(float4*)&AfU[base + 4];
            }
#pragma unroll
            for (int cs = 0; cs < 2; ++cs) {
                const int base = (wv * 32 + cs * 16 + fm) * 36 + 8 * kg;
                *(float4*)&bfr[cs][0] = *(float4*)&WfU[base];
                *(float4*)&bfr[cs][4] = *(float4*)&WfU[base + 4];
            }
#pragma unroll
            for (int q = 0; q < 8; ++q) {
                double aq0 = (double)afr[0][q], aq1 = (double)afr[1][q];
                double aq2 = (double)afr[2][q], aq3 = (double)afr[3][q];
                double bq0 = (double)bfr[0][q], bq1 = (double)bfr[1][q];
                acc.m[0][0] = __builtin_amdgcn_mfma_f64_16x16x4f64(aq0, bq0, acc.m[0][0], 0, 0, 0);
                acc.m[0][1] = __builtin_amdgcn_mfma_f64_16x16x4f64(aq0, bq1, acc.m[0][1], 0, 0, 0);
                acc.m[1][0] = __builtin_amdgcn_mfma_f64_16x16x4f64(aq1, bq0, acc.m[1][0], 0, 0, 0);
                acc.m[1][1] = __builtin_amdgcn_mfma_f64_16x16x4f64(aq1, bq1, acc.m[1][1], 0, 0, 0);
                acc.m[2][0] = __builtin_amdgcn_mfma_f64_16x16x4f64(aq2, bq0, acc.m[2][0], 0, 0, 0);
                acc.m[2][1] = __builtin_amdgcn_mfma_f64_16x16x4f64(aq2, bq1, acc.m[2][1], 0, 0, 0);
                acc.m[3][0] = __builtin_amdgcn_mfma_f64_16x16x4f64(aq3, bq0, acc.m[3][0], 0, 0, 0);
                acc.m[3][1] = __builtin_amdgcn_mfma_f64_16x16x4f64(aq3, bq1, acc.m[3][1], 0, 0, 0);
            }
        } else {
#pragma unroll
            for (int k = 0; k < KT; ++k) {
                float4 af  = *(float4*)&AfU[k * 68 + ty * 4];
                float4 bfa = *(float4*)&WfU[k * 132 + tx * 4];
                float4 bfb = *(float4*)&WfU[k * 132 + 64 + tx * 4];
                double a_[4] = {(double)af.x, (double)af.y, (double)af.z, (double)af.w};
                double b_[8] = {(double)bfa.x, (double)bfa.y, (double)bfa.z, (double)bfa.w,
                                (double)bfb.x, (double)bfb.y, (double)bfb.z, (double)bfb.w};
#pragma unroll
                for (int r = 0; r < 4; ++r)
#pragma unroll
                    for (int c = 0; c < 8; ++c)
                        acc.v[r][c] = fma(a_[r], b_[c], acc.v[r][c]);
            }
        }
        __syncthreads();
    }

    // ---------- epilogue: f64 sigmoid, round to f32 ----------
    if (useMfma) {
        // D: lane,reg r -> row 4*kg+r (within 16), col fm
#pragma unroll
        for (int rs = 0; rs < 4; ++rs)
#pragma unroll
            for (int cs = 0; cs < 2; ++cs)
#pragma unroll
                for (int r = 0; r < 4; ++r) {
                    const int rr = mBase + rs * 16 + 4 * kg + r;
                    const int cc = eBase + wv * 32 + cs * 16 + fm;
                    double s = 1.0 / (1.0 + exp(-acc.m[rs][cs][r]));
                    scores[(size_t)rr * N_EXP + cc] = (float)s;
                }
    } else {
#pragma unroll
        for (int r = 0; r < 4; ++r) {
            const int rr = mBase + ty * 4 + r;
            float* dst = scores + (size_t)rr * N_EXP + eBase;
            float4 o0, o1;
            o0.x = (float)(1.0 / (1.0 + exp(-acc.v[r][0])));
            o0.y = (float)(1.0 / (1.0 + exp(-acc.v[r][1])));
            o0.z = (float)(1.0 / (1.0 + exp(-acc.v[r][2])));
            o0.w = (float)(1.0 / (1.0 + exp(-acc.v[r][3])));
            o1.x = (float)(1.0 / (1.0 + exp(-acc.v[r][4])));
            o1.y = (float)(1.0 / (1.0 + exp(-acc.v[r][5])));
            o1.z = (float)(1.0 / (1.0 + exp(-acc.v[r][6])));
            o1.w = (float)(1.0 / (1.0 + exp(-acc.v[r][7])));
            *(float4*)(dst + tx * 4) = o0;
            *(float4*)(dst + 64 + tx * 4) = o1;
        }
    }
}

// One wave (64 lanes) per row; 4 experts per lane (experts lane*4 .. lane*4+3).
// Group g = lane>>3 (8 lanes x 4 experts = 32 experts/group, 8 groups).
// All comparisons in f32, matching the reference's post-sigmoid f32 math exactly.
__global__ __launch_bounds__(256)
void router_topk_kernel(const float* __restrict__ scores, const float* __restrict__ bias,
                        float* __restrict__ out) {
    const int lane = threadIdx.x & 63;
    const int row = (blockIdx.x * blockDim.x + threadIdx.x) >> 6;

    float4 s4 = *(const float4*)(scores + (size_t)row * N_EXP + lane * 4);
    float4 b4 = *(const float4*)(bias + lane * 4);
    float sc[4]  = {s4.x, s4.y, s4.z, s4.w};
    float sfc[4] = {sc[0] + b4.x, sc[1] + b4.y, sc[2] + b4.z, sc[3] + b4.w};

    // per-group top-2 of scores_for_choice
    float m1 = -1e30f, m2 = -1e30f;
#pragma unroll
    for (int i = 0; i < 4; ++i) {
        float v = sfc[i];
        if (v > m1) { m2 = m1; m1 = v; }
        else if (v > m2) m2 = v;
    }
#pragma unroll
    for (int off = 1; off <= 4; off <<= 1) {  // butterfly within 8-lane group
        float o1 = __shfl_xor(m1, off);
        float o2 = __shfl_xor(m2, off);
        float n1 = fmaxf(m1, o1);
        float n2 = fmaxf(fminf(m1, o1), fmaxf(m2, o2));
        m1 = n1; m2 = n2;
    }
    float gs = m1 + m2;         // group score (all 8 lanes of the group agree)
    int g = lane >> 3;
    // rank of my group among the 8 (ties -> lower group index, like jax top_k)
    int rank = 0;
#pragma unroll
    for (int j = 0; j < 8; ++j) {
        float gj = __shfl(gs, j * 8);
        rank += (gj > gs || (gj == gs && j < g)) ? 1 : 0;
    }
    bool sel = rank < 4;
    float mv[4];
#pragma unroll
    for (int i = 0; i < 4; ++i) mv[i] = sel ? sfc[i] : 0.0f;

    // 8 rounds of wave-wide argmax (stable: ties -> lowest expert index)
    float wsum = 0.f;
    float myIdxF = 0.f, myW = 0.f;
    for (int it = 0; it < 8; ++it) {
        float bv = mv[0]; int bi = 0;
#pragma unroll
        for (int i = 1; i < 4; ++i)
            if (mv[i] > bv) { bv = mv[i]; bi = i; }
        int bidx = lane * 4 + bi;
        float bsc = sc[bi];   // un-biased sigmoid score rides along
#pragma unroll
        for (int off = 1; off <= 32; off <<= 1) {
            float ov = __shfl_xor(bv, off);
            int   oi = __shfl_xor(bidx, off);
            float os = __shfl_xor(bsc, off);
            if (ov > bv || (ov == bv && oi < bidx)) { bv = ov; bidx = oi; bsc = os; }
        }
        wsum += bsc;
        if (lane == it) { myIdxF = (float)bidx; myW = bsc; }
        if ((bidx >> 2) == lane) mv[bidx & 3] = -1e30f;  // owner clears winner
    }
    if (lane < 8) {
        out[(size_t)row * 8 + lane] = myIdxF;                                    // indices (as f32)
        out[(size_t)B_ROWS * 8 + (size_t)row * 8 + lane] = myW * (2.5f / wsum);  // weights
    }
}

extern "C" void kernel_launch(void* const* d_in, const int* in_sizes, int n_in,
                              void* d_out, int out_size, void* d_ws, size_t ws_size,
                              hipStream_t stream) {
    const float* hs   = (const float*)d_in[0];
    const float* w    = (const float*)d_in[1];
    const float* bias = (const float*)d_in[2];
    float* out = (float*)d_out;
    float* scores = (float*)d_ws;  // 16384*256*4 = 16 MB scratch

    dim3 g1(B_ROWS / MT, N_EXP / ET);  // (256, 2)
    router_gemm<<<g1, 256, 0, stream>>>(hs, w, scores);
    router_topk_kernel<<<B_ROWS / 4, 256, 0, stream>>>(scores, bias, out);
}

// Round 4
// 1589.147 us; speedup vs baseline: 1.2495x; 1.2495x over previous
//
#include <hip/hip_runtime.h>
#include <math.h>

#define B_ROWS 16384
#define H_DIM 7168
#define N_EXP 256
#define KT 32
#define MT 64
#define ET 128

using v4d = __attribute__((ext_vector_type(4))) double;

// Router GEMM, f64 accumulation. Fast path uses v_mfma_f64_16x16x4 with a
// RUNTIME-DECODED result layout:
//   We always feed lane l the A element (16-idx = l&15, k-slot = l>>4) and the
//   B element likewise. Three register-only probe MFMAs then (a) decode, for
//   each (lane, reg), which (A-16-idx mA, B-16-idx mB) lands there, and
//   (b) verify with an asymmetric exact-integer pattern that the k-slots of A
//   and B pair correctly. The epilogue stores at the decoded coordinates, so
//   the kernel is correct for ANY bijective hardware fragment layout.
//   Any decode/verify failure -> proven VALU fallback (bit-identical math).
// Numerics: products exact in f64, all adds f64 (MFMA sums 4/step, steps
// chained) -> f64 sigmoid -> round to f32: matches reference scores bit-exactly.
__global__ __launch_bounds__(256, 2)
void router_gemm(const float* __restrict__ hs, const float* __restrict__ w,
                 float* __restrict__ scores) {
    // f64 region for MFMA path; aliased as f32 arrays for the VALU fallback.
    __shared__ double LdsD[64 * 33 + 128 * 33];   // 50688 B
    __shared__ int okSh;
    double* Ad = LdsD;                  // [64][33] f64, k stored permuted
    double* Wd = LdsD + 64 * 33;        // [128][33] f64
    float* Af = (float*)LdsD;           // VALU: [32][68] f32
    float* Wf = ((float*)LdsD) + 2304;  // VALU: [32][132] f32

    const int t = threadIdx.x;
    const int lane = t & 63;
    const int wv = t >> 6;        // wave 0..3 -> 32-expert slab
    const int fm = lane & 15;     // our A/B 16-index
    const int kg = lane >> 4;     // our k-slot 0..3
    const int tx = t & 15;        // valu: expert group
    const int ty = t >> 4;        // valu: row group
    const int row8 = t >> 3;      // staging row 0..31
    const int kq8 = t & 7;        // staging k-quarter 0..7

    const int mBase = blockIdx.x * MT;
    const int eBase = blockIdx.y * ET;
    const float* hsp = hs + (size_t)mBase * H_DIM;
    const float* wp  = w  + (size_t)eBase * H_DIM;

    // ---------- runtime layout decode + verification (register-only) ----------
    v4d z = {0.0, 0.0, 0.0, 0.0};
    v4d d1 = __builtin_amdgcn_mfma_f64_16x16x4f64((double)(fm + 1), 1.0, z, 0, 0, 0);
    v4d d2 = __builtin_amdgcn_mfma_f64_16x16x4f64(1.0, (double)(fm + 1), z, 0, 0, 0);
    v4d d3 = __builtin_amdgcn_mfma_f64_16x16x4f64((double)(4 * fm + kg + 1),
                                                  (double)(8 * fm + 3 * kg + 5), z, 0, 0, 0);
    bool ok = true;
    int mA[4], mB[4];
#pragma unroll
    for (int r = 0; r < 4; ++r) {
        double v1 = d1[r], v2 = d2[r];
        int a_ = -1, b_ = -1;
        if (v1 >= 4.0 && v1 <= 64.0 && v2 >= 4.0 && v2 <= 64.0) {
            a_ = (int)(v1 * 0.25) - 1;
            b_ = (int)(v2 * 0.25) - 1;
            if (v1 != 4.0 * (double)(a_ + 1) || v2 != 4.0 * (double)(b_ + 1)) ok = false;
        } else ok = false;
        if (a_ < 0) ok = false;
        else {
            double P = 4.0 * (double)a_ + 1.0, Q = 8.0 * (double)b_ + 5.0;
            if (d3[r] != 4.0 * P * Q + 18.0 * P + 6.0 * Q + 42.0) ok = false;
        }
        mA[r] = a_; mB[r] = b_;
    }
    if (t == 0) okSh = 1;
    __syncthreads();
    if (!ok) okSh = 0;   // benign same-value race
    __syncthreads();
    const bool useMfma = (okSh != 0);

    // ---------- accumulators (unioned: only one path live) ----------
    union AccU { double v[4][8]; v4d m[4][2]; } acc;
#pragma unroll
    for (int r = 0; r < 4; ++r)
#pragma unroll
        for (int c = 0; c < 8; ++c) acc.v[r][c] = 0.0;

    // ---------- global prefetch of chunk 0 ----------
    float haf[2][4], waf[4][4];
#pragma unroll
    for (int i = 0; i < 2; ++i)
        *(float4*)&haf[i][0] = *(const float4*)(hsp + (size_t)(i * 32 + row8) * H_DIM + 4 * kq8);
#pragma unroll
    for (int i = 0; i < 4; ++i)
        *(float4*)&waf[i][0] = *(const float4*)(wp + (size_t)(i * 32 + row8) * H_DIM + 4 * kq8);

    const int NCHUNK = H_DIM / KT;  // 224
    for (int ch = 0; ch < NCHUNK; ++ch) {
        // registers -> LDS
        if (useMfma) {
            // store k = 4*kq8+j at position p(k) = 8*(k&3) + (k>>2) = 8*j + kq8
            // -> fragment reads are contiguous in q (64B = 4x b128, 2-way banks)
#pragma unroll
            for (int i = 0; i < 2; ++i)
#pragma unroll
                for (int j = 0; j < 4; ++j)
                    Ad[(i * 32 + row8) * 33 + 8 * j + kq8] = (double)haf[i][j];
#pragma unroll
            for (int i = 0; i < 4; ++i)
#pragma unroll
                for (int j = 0; j < 4; ++j)
                    Wd[(i * 32 + row8) * 33 + 8 * j + kq8] = (double)waf[i][j];
        } else {
#pragma unroll
            for (int i = 0; i < 2; ++i)
#pragma unroll
                for (int j = 0; j < 4; ++j)
                    Af[(4 * kq8 + j) * 68 + i * 32 + row8] = haf[i][j];
#pragma unroll
            for (int i = 0; i < 4; ++i)
#pragma unroll
                for (int j = 0; j < 4; ++j)
                    Wf[(4 * kq8 + j) * 132 + i * 32 + row8] = waf[i][j];
        }
        __syncthreads();
        // prefetch next chunk (overlaps compute)
        if (ch + 1 < NCHUNK) {
            const float* hp2 = hsp + (size_t)(ch + 1) * KT;
            const float* wp2 = wp  + (size_t)(ch + 1) * KT;
#pragma unroll
            for (int i = 0; i < 2; ++i)
                *(float4*)&haf[i][0] = *(const float4*)(hp2 + (size_t)(i * 32 + row8) * H_DIM + 4 * kq8);
#pragma unroll
            for (int i = 0; i < 4; ++i)
                *(float4*)&waf[i][0] = *(const float4*)(wp2 + (size_t)(i * 32 + row8) * H_DIM + 4 * kq8);
        }
        if (useMfma) {
            // fragments: lane reads its 8 q-values contiguously (4x ds_read_b128)
            double afr[4][8], bfr[2][8];
#pragma unroll
            for (int rs = 0; rs < 4; ++rs) {
                const double* p = Ad + (rs * 16 + fm) * 33 + 8 * kg;
#pragma unroll
                for (int q = 0; q < 8; ++q) afr[rs][q] = p[q];
            }
#pragma unroll
            for (int cs = 0; cs < 2; ++cs) {
                const double* p = Wd + (wv * 32 + cs * 16 + fm) * 33 + 8 * kg;
#pragma unroll
                for (int q = 0; q < 8; ++q) bfr[cs][q] = p[q];
            }
#pragma unroll
            for (int q = 0; q < 8; ++q) {
                acc.m[0][0] = __builtin_amdgcn_mfma_f64_16x16x4f64(afr[0][q], bfr[0][q], acc.m[0][0], 0, 0, 0);
                acc.m[0][1] = __builtin_amdgcn_mfma_f64_16x16x4f64(afr[0][q], bfr[1][q], acc.m[0][1], 0, 0, 0);
                acc.m[1][0] = __builtin_amdgcn_mfma_f64_16x16x4f64(afr[1][q], bfr[0][q], acc.m[1][0], 0, 0, 0);
                acc.m[1][1] = __builtin_amdgcn_mfma_f64_16x16x4f64(afr[1][q], bfr[1][q], acc.m[1][1], 0, 0, 0);
                acc.m[2][0] = __builtin_amdgcn_mfma_f64_16x16x4f64(afr[2][q], bfr[0][q], acc.m[2][0], 0, 0, 0);
                acc.m[2][1] = __builtin_amdgcn_mfma_f64_16x16x4f64(afr[2][q], bfr[1][q], acc.m[2][1], 0, 0, 0);
                acc.m[3][0] = __builtin_amdgcn_mfma_f64_16x16x4f64(afr[3][q], bfr[0][q], acc.m[3][0], 0, 0, 0);
                acc.m[3][1] = __builtin_amdgcn_mfma_f64_16x16x4f64(afr[3][q], bfr[1][q], acc.m[3][1], 0, 0, 0);
            }
        } else {
#pragma unroll
            for (int k = 0; k < KT; ++k) {
                float4 af  = *(float4*)&Af[k * 68 + ty * 4];
                float4 bfa = *(float4*)&Wf[k * 132 + tx * 4];
                float4 bfb = *(float4*)&Wf[k * 132 + 64 + tx * 4];
                double a_[4] = {(double)af.x, (double)af.y, (double)af.z, (double)af.w};
                double b_[8] = {(double)bfa.x, (double)bfa.y, (double)bfa.z, (double)bfa.w,
                                (double)bfb.x, (double)bfb.y, (double)bfb.z, (double)bfb.w};
#pragma unroll
                for (int r = 0; r < 4; ++r)
#pragma unroll
                    for (int c = 0; c < 8; ++c)
                        acc.v[r][c] = fma(a_[r], b_[c], acc.v[r][c]);
            }
        }
        __syncthreads();
    }

    // ---------- epilogue: f64 sigmoid, round to f32 ----------
    if (useMfma) {
        // store at DECODED coordinates: reg r of this lane holds the result for
        // A-16-idx mA[r], B-16-idx mB[r] of each (rs, cs) sub-tile.
#pragma unroll
        for (int rs = 0; rs < 4; ++rs)
#pragma unroll
            for (int cs = 0; cs < 2; ++cs)
#pragma unroll
                for (int r = 0; r < 4; ++r) {
                    const int rr = mBase + rs * 16 + mA[r];
                    const int cc = eBase + wv * 32 + cs * 16 + mB[r];
                    double s = 1.0 / (1.0 + exp(-acc.m[rs][cs][r]));
                    scores[(size_t)rr * N_EXP + cc] = (float)s;
                }
    } else {
#pragma unroll
        for (int r = 0; r < 4; ++r) {
            const int rr = mBase + ty * 4 + r;
            float* dst = scores + (size_t)rr * N_EXP + eBase;
            float4 o0, o1;
            o0.x = (float)(1.0 / (1.0 + exp(-acc.v[r][0])));
            o0.y = (float)(1.0 / (1.0 + exp(-acc.v[r][1])));
            o0.z = (float)(1.0 / (1.0 + exp(-acc.v[r][2])));
            o0.w = (float)(1.0 / (1.0 + exp(-acc.v[r][3])));
            o1.x = (float)(1.0 / (1.0 + exp(-acc.v[r][4])));
            o1.y = (float)(1.0 / (1.0 + exp(-acc.v[r][5])));
            o1.z = (float)(1.0 / (1.0 + exp(-acc.v[r][6])));
            o1.w = (float)(1.0 / (1.0 + exp(-acc.v[r][7])));
            *(float4*)(dst + tx * 4) = o0;
            *(float4*)(dst + 64 + tx * 4) = o1;
        }
    }
}

// One wave (64 lanes) per row; 4 experts per lane (experts lane*4 .. lane*4+3).
// Group g = lane>>3 (8 lanes x 4 experts = 32 experts/group, 8 groups).
// All comparisons in f32, matching the reference's post-sigmoid f32 math exactly.
__global__ __launch_bounds__(256)
void router_topk_kernel(const float* __restrict__ scores, const float* __restrict__ bias,
                        float* __restrict__ out) {
    const int lane = threadIdx.x & 63;
    const int row = (blockIdx.x * blockDim.x + threadIdx.x) >> 6;

    float4 s4 = *(const float4*)(scores + (size_t)row * N_EXP + lane * 4);
    float4 b4 = *(const float4*)(bias + lane * 4);
    float sc[4]  = {s4.x, s4.y, s4.z, s4.w};
    float sfc[4] = {sc[0] + b4.x, sc[1] + b4.y, sc[2] + b4.z, sc[3] + b4.w};

    // per-group top-2 of scores_for_choice
    float m1 = -1e30f, m2 = -1e30f;
#pragma unroll
    for (int i = 0; i < 4; ++i) {
        float v = sfc[i];
        if (v > m1) { m2 = m1; m1 = v; }
        else if (v > m2) m2 = v;
    }
#pragma unroll
    for (int off = 1; off <= 4; off <<= 1) {  // butterfly within 8-lane group
        float o1 = __shfl_xor(m1, off);
        float o2 = __shfl_xor(m2, off);
        float n1 = fmaxf(m1, o1);
        float n2 = fmaxf(fminf(m1, o1), fmaxf(m2, o2));
        m1 = n1; m2 = n2;
    }
    float gs = m1 + m2;         // group score (all 8 lanes of the group agree)
    int g = lane >> 3;
    // rank of my group among the 8 (ties -> lower group index, like jax top_k)
    int rank = 0;
#pragma unroll
    for (int j = 0; j < 8; ++j) {
        float gj = __shfl(gs, j * 8);
        rank += (gj > gs || (gj == gs && j < g)) ? 1 : 0;
    }
    bool sel = rank < 4;
    float mv[4];
#pragma unroll
    for (int i = 0; i < 4; ++i) mv[i] = sel ? sfc[i] : 0.0f;

    // 8 rounds of wave-wide argmax (stable: ties -> lowest expert index)
    float wsum = 0.f;
    float myIdxF = 0.f, myW = 0.f;
    for (int it = 0; it < 8; ++it) {
        float bv = mv[0]; int bi = 0;
#pragma unroll
        for (int i = 1; i < 4; ++i)
            if (mv[i] > bv) { bv = mv[i]; bi = i; }
        int bidx = lane * 4 + bi;
        float bsc = sc[bi];   // un-biased sigmoid score rides along
#pragma unroll
        for (int off = 1; off <= 32; off <<= 1) {
            float ov = __shfl_xor(bv, off);
            int   oi = __shfl_xor(bidx, off);
            float os = __shfl_xor(bsc, off);
            if (ov > bv || (ov == bv && oi < bidx)) { bv = ov; bidx = oi; bsc = os; }
        }
        wsum += bsc;
        if (lane == it) { myIdxF = (float)bidx; myW = bsc; }
        if ((bidx >> 2) == lane) mv[bidx & 3] = -1e30f;  // owner clears winner
    }
    if (lane < 8) {
        out[(size_t)row * 8 + lane] = myIdxF;                                    // indices (as f32)
        out[(size_t)B_ROWS * 8 + (size_t)row * 8 + lane] = myW * (2.5f / wsum);  // weights
    }
}

extern "C" void kernel_launch(void* const* d_in, const int* in_sizes, int n_in,
                              void* d_out, int out_size, void* d_ws, size_t ws_size,
                              hipStream_t stream) {
    const float* hs   = (const float*)d_in[0];
    const float* w    = (const float*)d_in[1];
    const float* bias = (const float*)d_in[2];
    float* out = (float*)d_out;
    float* scores = (float*)d_ws;  // 16384*256*4 = 16 MB scratch

    dim3 g1(B_ROWS / MT, N_EXP / ET);  // (256, 2)
    router_gemm<<<g1, 256, 0, stream>>>(hs, w, scores);
    router_topk_kernel<<<B_ROWS / 4, 256, 0, stream>>>(scores, bias, out);
}